// Round 10
// baseline (925.706 us; speedup 1.0000x reference)
//
#include <hip/hip_runtime.h>
#include <hip/hip_cooperative_groups.h>
#include <stdint.h>

namespace cg = cooperative_groups;

#define C_ITEMS 16384
#define NCLS 16
#define HSTRIDE 16386   // AP hist entries per class (opt in [1, P+1])
#define NB 65536        // negative sort buckets per class (ordkey >> 16)
#define BSH 16
#define GRID 512
#define BLK 256
#define GSTR (GRID * BLK)   // 131072

// ---- workspace layout (bytes) ----
// col[0,1M) spos[1M,2M) sneg[2M,3M) pack[3M,4M) hist+scalars+h1[4M,~9.44M) ppk[10M,12M)
static constexpr size_t OFF_COL  = 0;
static constexpr size_t OFF_SPOS = 1u << 20;
static constexpr size_t OFF_SNEG = 2u << 20;
static constexpr size_t OFF_PACK = 3u << 20;
static constexpr size_t OFF_HIST = 4u << 20;
static constexpr size_t OFF_CNT  = OFF_HIST + (size_t)NCLS * HSTRIDE * 4;
static constexpr size_t OFF_ACCS = OFF_CNT + 64;
static constexpr size_t OFF_ACCV = OFF_ACCS + 128;
static constexpr size_t OFF_TOT  = OFF_ACCV + 128;
static constexpr size_t OFF_PC   = OFF_TOT + 8;
static constexpr size_t OFF_H1   = (OFF_PC + 64 + 255) & ~(size_t)255;
static constexpr size_t ZERO_END = OFF_H1 + ((size_t)NCLS * NB * 4);
static constexpr size_t ZERO_BYTES = ZERO_END - OFF_HIST;   // ~5.25 MB
static constexpr size_t OFF_PPK  = 10u << 20;               // 16*16384 u64 positive keys
// aopt (16*512 u32) aliases OFF_PPK: written in phase 5 strictly after phase 2
// consumed ppk (grid.sync-ordered within the cooperative kernel).

__device__ __forceinline__ unsigned ordkey(float f) {
  unsigned b = __float_as_uint(f);
  return (b & 0x80000000u) ? ~b : (b | 0x80000000u);   // monotone float->uint
}

#define SCAP 2048
#define PCAP 2048
#define HCAP 2048
#define ASTEP 64
#define ABITS 6

// ============================================================================
// Single cooperative kernel: 9 phases separated by grid.sync().
// All phase math is bit-identical to the R9-validated multi-kernel pipeline;
// only thread->work mappings changed (all permutation-invariant).
// Grid 512x256 = 2 blocks/CU: co-residency guaranteed (18.7KB LDS, low VGPR).
// ============================================================================
__global__ __launch_bounds__(BLK) void k_all(const float* __restrict__ scores,
                                             const int* __restrict__ labels,
                                             char* __restrict__ ws,
                                             float* __restrict__ out) {
  cg::grid_group grid = cg::this_grid();
  float* col      = (float*)(ws + OFF_COL);
  float* spos     = (float*)(ws + OFF_SPOS);
  float* sneg     = (float*)(ws + OFF_SNEG);
  unsigned* pack  = (unsigned*)(ws + OFF_PACK);
  unsigned* hist  = (unsigned*)(ws + OFF_HIST);
  double* accS    = (double*)(ws + OFF_ACCS);
  double* accV    = (double*)(ws + OFF_ACCV);
  double* total   = (double*)(ws + OFF_TOT);
  unsigned* pcnt  = (unsigned*)(ws + OFF_PC);
  unsigned* h1    = (unsigned*)(ws + OFF_H1);
  unsigned long long* ppk = (unsigned long long*)(ws + OFF_PPK);
  unsigned* aopt  = (unsigned*)(ws + OFF_PPK);   // alias, used after ppk dead

  int b = blockIdx.x, tid = threadIdx.x;
  int gt = b * BLK + tid;

  __shared__ __align__(16) char smem[18688];     // union buffer across phases

  // ---- P0: zero hist..h1 (harness poisons ws) ----
  {
    unsigned* z = (unsigned*)(ws + OFF_HIST);
    int n = (int)(ZERO_BYTES / 4);
    for (int t = gt; t < n; t += GSTR) z[t] = 0u;
  }
  __threadfence(); grid.sync();

  // ---- P1: transpose + negative bucket histogram (all) + positive collect (b<64) ----
  for (int t = gt; t < C_ITEMS * NCLS; t += GSTR) {
    float v = scores[t];
    int i = t >> 4, c = t & 15;
    col[(c << 14) | i] = v;
    if (labels[i] != c) atomicAdd(&h1[(c << 16) + (ordkey(v) >> BSH)], 1u);
  }
  if (b < 64) {   // two-level reservation collect, identical to validated k_posc
    unsigned* lc   = (unsigned*)smem;
    unsigned* base = lc + NCLS;
    if (tid < NCLS) lc[tid] = 0;
    __syncthreads();
    int i = b * 256 + tid;
    int c = labels[i] & 15;
    float v = scores[i * NCLS + c];
    unsigned loc = atomicAdd(&lc[c], 1u);
    __syncthreads();
    if (tid < NCLS) base[tid] = lc[tid] ? atomicAdd(&pcnt[tid], lc[tid]) : 0u;
    __syncthreads();
    ppk[(c << 14) + base[c] + loc] = ((unsigned long long)(~ordkey(v)) << 32) | (unsigned)i;
  }
  __threadfence(); grid.sync();

  // ---- P2: per-class 64K-bucket exclusive scan (b<16) + positive rank (16<=b<48) ----
  if (b < NCLS) {
    unsigned* h = h1 + ((size_t)b << 16);
    unsigned* part = (unsigned*)smem;   // 256 u32
    unsigned base0 = (unsigned)tid << 8;   // 256 buckets/thread
    unsigned s = 0;
    for (int q = 0; q < 256; ++q) s += h[base0 + q];
    part[tid] = s;
    __syncthreads();
    for (int off = 1; off < 256; off <<= 1) {
      unsigned v = (tid >= off) ? part[tid - off] : 0u;
      __syncthreads();
      part[tid] += v;
      __syncthreads();
    }
    unsigned running = part[tid] - s;
    for (int q = 0; q < 256; ++q) {
      unsigned tmp = h[base0 + q];
      h[base0 + q] = running;
      running += tmp;
    }
  } else if (b < 48) {
    // keys unique -> count-smaller is permutation-invariant
    int c = (b - 16) >> 1, half = (b - 16) & 1;
    unsigned P = pcnt[c];
    unsigned long long* pk = (unsigned long long*)smem;   // 2048 u64 = 16KB
    const unsigned long long* src = ppk + ((size_t)c << 14);
    if (P <= PCAP) {
      for (unsigned t = tid; t < P; t += 256) pk[t] = src[t];
      __syncthreads();
      for (unsigned q = (unsigned)(tid * 2 + half); q < P; q += 512) {
        unsigned long long k64 = pk[q];
        unsigned cq = 0;
        for (unsigned t = 0; t < P; ++t) cq += (pk[t] < k64) ? 1u : 0u;
        unsigned i = (unsigned)(k64 & 0xFFFFFFFFu);
        spos[(c << 14) + cq] = col[(c << 14) + (int)i];
      }
    } else {   // safety fallback (won't trigger for this input)
      for (unsigned q = (unsigned)(tid * 2 + half); q < P; q += 512) {
        unsigned long long k64 = src[q];
        unsigned cq = 0;
        for (unsigned t = 0; t < P; ++t) cq += (src[t] < k64) ? 1u : 0u;
        unsigned i = (unsigned)(k64 & 0xFFFFFFFFu);
        spos[(c << 14) + cq] = col[(c << 14) + (int)i];
      }
    }
  }
  __threadfence(); grid.sync();

  // ---- P3: scatter negatives (h1[b] becomes bucket END) ----
  for (int t = gt; t < C_ITEMS * NCLS; t += GSTR) {
    int c = t >> 14, i = t & 16383;
    if (labels[i] != c) {
      unsigned k = ordkey(col[t]);
      unsigned p = atomicAdd(&h1[(c << 16) + (k >> BSH)], 1u);
      pack[(c << 14) + p] = (k << 16) | (unsigned)i;
    }
  }
  __threadfence(); grid.sync();

  // ---- P4: rankfine -> sneg by ascending rank ----
  for (int t = gt; t < C_ITEMS * NCLS; t += GSTR) {
    int c = t >> 14, i = t & 16383;
    if (labels[i] != c) {
      float v = col[t];
      unsigned k = ordkey(v);
      unsigned bb = k >> BSH;
      const unsigned* hb = h1 + ((size_t)c << 16);
      unsigned start = bb ? hb[bb - 1] : 0u;
      unsigned end = hb[bb];
      unsigned mine = (k << 16) | (unsigned)i;
      const unsigned* pk2 = pack + (c << 14);
      unsigned cnt = start;
      for (unsigned q = start; q < end; ++q) cnt += (pk2[q] < mine) ? 1u : 0u;
      sneg[(c << 14) + (int)cnt] = v;
    }
  }
  __threadfence(); grid.sync();

  // ---- P5: anchors (b<16; one class per block). opt_j monotone non-increasing
  //      in j (the property the reference's quickselect D&C exploits) =>
  //      anchors every ASTEP ranks bracket all intermediate opts. ----
  if (b < NCLS) {
    int c = b;
    int P = (int)pcnt[c];
    int N = C_ITEMS - P;
    if (P > 0 && N > 0) {
      float* sp = (float*)smem;
      int stageN = (P <= SCAP) ? P : 0;
      for (int t = tid; t < stageN; t += 256) sp[t] = spos[(c << 14) + t];
      __syncthreads();
      int T = (N + ASTEP - 1) / ASTEP + 1;
      float invP = 1.0f / (float)P;
      float coef = 2.0f / ((float)P * (float)N);
      for (int ta = tid; ta < T; ta += 256) {
        int j0 = min(ta * ASTEP, N - 1);
        float v = sneg[(c << 14) + j0];
        float a = coef * v;
        float fcnt = (float)(j0 + P + 1);
        float s = 0.0f, best = 0.0f;
        int besti = P;
        if (P <= SCAP) {
          for (int q = P - 1; q >= 0; --q) {
            float spv = sp[q];
            float r = __builtin_amdgcn_rcpf(fcnt);
            float delta = fmaf(invP, r, fmaf(-coef, spv, a));
            s += delta;
            if (s >= best) { best = s; besti = q; }
            fcnt -= 1.0f;
          }
        } else {
          const float* spg = spos + ((size_t)c << 14);
          for (int q = P - 1; q >= 0; --q) {
            float spv = spg[q];
            float r = __builtin_amdgcn_rcpf(fcnt);
            float delta = fmaf(invP, r, fmaf(-coef, spv, a));
            s += delta;
            if (s >= best) { best = s; besti = q; }
            fcnt -= 1.0f;
          }
        }
        aopt[(c << 9) + ta] = (unsigned)(besti + 1);
      }
    }
  }
  __threadfence(); grid.sync();

  // ---- P6: bracketed argmax + histogram + minus-side sums ----
  // 512 blocks = 16 classes x 32 chunks of 512 j's (2 per thread).
  {
    int c = b >> 5;
    int P = (int)pcnt[c];
    int N = C_ITEMS - P;
    if (P > 0 && N > 0) {
      float*    sp  = (float*)smem;              // 8KB
      unsigned* lh  = (unsigned*)(smem + 8192);  // 8KB
      double*   red = (double*)(smem + 16384);   // 2KB
      int jbase = (b & 31) * 512;
      int stageN = (P <= SCAP) ? P : 0;
      int zn2 = (P + 2 <= HCAP) ? (P + 2) : 0;
      for (int t = tid; t < stageN; t += 256) sp[t] = spos[(c << 14) + t];
      for (int t = tid; t < zn2; t += 256) lh[t] = 0u;
      __syncthreads();
      float invP = 1.0f / (float)P;
      float coef = 2.0f / ((float)P * (float)N);
      double cmS = 0.0, svS = 0.0;
      for (int jj = 0; jj < 2; ++jj) {
        int j0 = jbase + jj * 256 + tid;
        bool active = (j0 < N);
        int opt = P + 1;
        float v = 0.0f;
        if (active) {
          v = sneg[(c << 14) + j0];
          int g = j0 >> ABITS;
          int hiA = (int)aopt[(c << 9) + g];
          if ((j0 & (ASTEP - 1)) == 0) {
            opt = hiA;                       // anchor rank: exact full-scan value
          } else {
            int loA = (int)aopt[(c << 9) + g + 1];
            int hi = min(hiA + 2, P + 1);    // +-2 absorbs float near-tie wobble
            int lo = max(loA - 2, 1);
            float a = coef * v;
            float s = 0.0f, best = 0.0f;
            int bestr = hi;                  // empty-suffix candidate at r=hi
            float fcnt = (float)(j0 + hi);
            if (P <= SCAP) {
              for (int k = hi - 1; k >= lo; --k) {
                float spv = sp[k - 1];
                float r = __builtin_amdgcn_rcpf(fcnt);
                float delta = fmaf(invP, r, fmaf(-coef, spv, a));
                s += delta;
                if (s >= best) { best = s; bestr = k; }
                fcnt -= 1.0f;
              }
            } else {
              const float* spg = spos + ((size_t)c << 14);
              for (int k = hi - 1; k >= lo; --k) {
                float spv = spg[k - 1];
                float r = __builtin_amdgcn_rcpf(fcnt);
                float delta = fmaf(invP, r, fmaf(-coef, spv, a));
                s += delta;
                if (s >= best) { best = s; bestr = k; }
                fcnt -= 1.0f;
              }
            }
            opt = bestr;
          }
          if (P + 2 <= HCAP) atomicAdd(&lh[opt], 1u);
          else atomicAdd(&hist[c * HSTRIDE + opt], 1u);
          cmS += (double)(P + 2 - 2 * opt) * (double)v;
          svS += (double)v;
        }
      }
      __syncthreads();
      if (P + 2 <= HCAP) {
        for (int t = tid; t < P + 2; t += 256)
          if (lh[t]) atomicAdd(&hist[c * HSTRIDE + t], lh[t]);
      }
      red[tid] = cmS; __syncthreads();
      for (int sh = 128; sh > 0; sh >>= 1) { if (tid < sh) red[tid] += red[tid + sh]; __syncthreads(); }
      if (tid == 0) atomicAdd(&accS[c], red[0]);
      __syncthreads();
      red[tid] = svS; __syncthreads();
      for (int sh = 128; sh > 0; sh >>= 1) { if (tid < sh) red[tid] += red[tid + sh]; __syncthreads(); }
      if (tid == 0) atomicAdd(&accV[c], red[0]);
    }
  }
  __threadfence(); grid.sync();

  // ---- P7: per-class finalize (b<16) ----
  if (b < NCLS) {
    int c = b;
    int P = (int)pcnt[c];
    int N = C_ITEMS - P;
    if (P > 0 && N > 0) {
      unsigned* sc = (unsigned*)smem;          // 1KB
      double*   red = (double*)(smem + 1024);  // 2KB
      const unsigned* h = hist + c * HSTRIDE;
      int M = P + 1;
      int L = (M + 255) / 256;
      int o0 = 1 + tid * L;
      int o1 = min(o0 + L, P + 2);
      unsigned part = 0;
      for (int o = o0; o < o1; ++o) part += h[o];
      sc[tid] = part;
      __syncthreads();
      if (tid == 0) {
        unsigned runp = 0;
        for (int t = 0; t < 256; ++t) { unsigned tmp = sc[t]; sc[t] = runp; runp += tmp; }
      }
      __syncthreads();
      unsigned run = sc[tid];
      double a1 = 0.0, a2 = 0.0, a3 = 0.0;
      for (int o = o0; o < o1; ++o) {
        run += h[o];
        if (o <= P) {
          int k0 = o - 1;
          double rp = 1.0 + (double)run;
          double spv = (double)spos[(c << 14) + k0];
          a1 += (double)(k0 + 1) / ((double)k0 + rp);
          a2 += spv * ((double)N + 2.0 - 2.0 * rp);
          a3 += spv;
        }
      }
      red[tid] = a1; __syncthreads();
      for (int s = 128; s > 0; s >>= 1) { if (tid < s) red[tid] += red[tid + s]; __syncthreads(); }
      double r1 = red[0]; __syncthreads();
      red[tid] = a2; __syncthreads();
      for (int s = 128; s > 0; s >>= 1) { if (tid < s) red[tid] += red[tid + s]; __syncthreads(); }
      double r2 = red[0]; __syncthreads();
      red[tid] = a3; __syncthreads();
      for (int s = 128; s > 0; s >>= 1) { if (tid < s) red[tid] += red[tid + s]; __syncthreads(); }
      double r3 = red[0];
      if (tid == 0) {
        double Pd = (double)P, Nd = (double)N;
        double FR  = r2 + accS[c];
        double FRs = Nd * r3 - Pd * accV[c];
        double lc  = (1.0 - r1 / Pd) + (FR - FRs) / (Pd * Nd);
        atomicAdd(total, lc);
      }
    }
  }
  __threadfence(); grid.sync();

  // ---- P8: output ----
  if (b == 0 && tid == 0) {
    double t = atomicAdd(total, 0.0);   // device-scope RMW read
    out[0] = (float)(t / (double)NCLS);
  }
}

// ============================================================================
// Fallback: the validated R9 multi-kernel pipeline (used only if the
// cooperative launch is rejected by the runtime/graph capture).
// ============================================================================
__global__ void k_zero(unsigned* __restrict__ p, int n) {
  int stride = gridDim.x * blockDim.x;
  for (int t = blockIdx.x * blockDim.x + threadIdx.x; t < n; t += stride) p[t] = 0u;
}

__global__ void k_prep(const float* __restrict__ scores, const int* __restrict__ labels,
                       float* __restrict__ col, unsigned* __restrict__ h1) {
  int t = blockIdx.x * 256 + threadIdx.x;
  float v = scores[t];
  int i = t >> 4, c = t & 15;
  col[(c << 14) | i] = v;
  if (labels[i] != c)
    atomicAdd(&h1[(c << 16) + (ordkey(v) >> BSH)], 1u);
}

__global__ void k_posc(const float* __restrict__ scores, const int* __restrict__ labels,
                       unsigned* __restrict__ pcnt, unsigned long long* __restrict__ ppk) {
  __shared__ unsigned lc[NCLS];
  __shared__ unsigned base[NCLS];
  int tid = threadIdx.x;
  if (tid < NCLS) lc[tid] = 0;
  __syncthreads();
  int i = blockIdx.x * 256 + tid;
  int c = labels[i] & 15;
  float v = scores[i * NCLS + c];
  unsigned loc = atomicAdd(&lc[c], 1u);
  __syncthreads();
  if (tid < NCLS) base[tid] = lc[tid] ? atomicAdd(&pcnt[tid], lc[tid]) : 0u;
  __syncthreads();
  ppk[(c << 14) + base[c] + loc] = ((unsigned long long)(~ordkey(v)) << 32) | (unsigned)i;
}

__global__ __launch_bounds__(1024) void k_mid(
    unsigned* __restrict__ h1, const float* __restrict__ col,
    const unsigned* __restrict__ pcnt, const unsigned long long* __restrict__ ppk,
    float* __restrict__ spos) {
  int b = blockIdx.x;
  int tid = threadIdx.x;
  __shared__ unsigned part[1024];
  __shared__ unsigned long long pk[PCAP];
  if (b < NCLS) {
    unsigned* h = h1 + ((size_t)b << 16);
    unsigned base = (unsigned)tid << 6;
    unsigned s = 0;
    for (int q = 0; q < 64; ++q) s += h[base + q];
    part[tid] = s;
    __syncthreads();
    for (int off = 1; off < 1024; off <<= 1) {
      unsigned v = (tid >= off) ? part[tid - off] : 0u;
      __syncthreads();
      part[tid] += v;
      __syncthreads();
    }
    unsigned running = part[tid] - s;
    for (int q = 0; q < 64; ++q) {
      unsigned tmp = h[base + q];
      h[base + q] = running;
      running += tmp;
    }
  } else {
    int c = b - NCLS;
    unsigned P = pcnt[c];
    const unsigned long long* src = ppk + ((size_t)c << 14);
    if (P <= PCAP) {
      for (unsigned t = tid; t < P; t += 1024) pk[t] = src[t];
      __syncthreads();
      for (unsigned q = tid; q < P; q += 1024) {
        unsigned long long k64 = pk[q];
        unsigned cq = 0;
        for (unsigned t = 0; t < P; ++t) cq += (pk[t] < k64) ? 1u : 0u;
        unsigned i = (unsigned)(k64 & 0xFFFFFFFFu);
        spos[(c << 14) + cq] = col[(c << 14) + (int)i];
      }
    } else {
      for (unsigned q = tid; q < P; q += 1024) {
        unsigned long long k64 = src[q];
        unsigned cq = 0;
        for (unsigned t = 0; t < P; ++t) cq += (src[t] < k64) ? 1u : 0u;
        unsigned i = (unsigned)(k64 & 0xFFFFFFFFu);
        spos[(c << 14) + cq] = col[(c << 14) + (int)i];
      }
    }
  }
}

__global__ void k_scatter(const float* __restrict__ col, const int* __restrict__ labels,
                          unsigned* __restrict__ h1, unsigned* __restrict__ pack) {
  int t = blockIdx.x * 256 + threadIdx.x;
  int c = t >> 14, i = t & 16383;
  if (labels[i] != c) {
    unsigned k = ordkey(col[t]);
    unsigned p = atomicAdd(&h1[(c << 16) + (k >> BSH)], 1u);
    pack[(c << 14) + p] = (k << 16) | (unsigned)i;
  }
}

__global__ void k_rankfine(const float* __restrict__ col, const int* __restrict__ labels,
                           const unsigned* __restrict__ h1, const unsigned* __restrict__ pack,
                           float* __restrict__ sneg) {
  int t = blockIdx.x * 256 + threadIdx.x;
  int c = t >> 14, i = t & 16383;
  if (labels[i] != c) {
    float v = col[t];
    unsigned k = ordkey(v);
    unsigned b = k >> BSH;
    const unsigned* hb = h1 + ((size_t)c << 16);
    unsigned start = b ? hb[b - 1] : 0u;
    unsigned end = hb[b];
    unsigned mine = (k << 16) | (unsigned)i;
    const unsigned* pk = pack + (c << 14);
    unsigned cnt = start;
    for (unsigned q = start; q < end; ++q) cnt += (pk[q] < mine) ? 1u : 0u;
    sneg[(c << 14) + (int)cnt] = v;
  }
}

__global__ void k_anchor(const unsigned* __restrict__ counts, const float* __restrict__ spos,
                         const float* __restrict__ sneg, unsigned* __restrict__ aopt) {
  int c = blockIdx.y;
  int P = (int)counts[c];
  int N = C_ITEMS - P;
  if (P == 0 || N == 0) return;
  int tid = threadIdx.x;
  __shared__ float sp[SCAP];
  int stageN = (P <= SCAP) ? P : 0;
  for (int t = tid; t < stageN; t += 64) sp[t] = spos[(c << 14) + t];
  __syncthreads();
  int ta = blockIdx.x * 64 + tid;
  int T = (N + ASTEP - 1) / ASTEP + 1;
  if (ta >= T) return;
  float invP = 1.0f / (float)P;
  float coef = 2.0f / ((float)P * (float)N);
  int j0 = min(ta * ASTEP, N - 1);
  float v = sneg[(c << 14) + j0];
  float a = coef * v;
  float fcnt = (float)(j0 + P + 1);
  float s = 0.0f, best = 0.0f;
  int besti = P;
  if (P <= SCAP) {
    for (int q = P - 1; q >= 0; --q) {
      float spv = sp[q];
      float r = __builtin_amdgcn_rcpf(fcnt);
      float delta = fmaf(invP, r, fmaf(-coef, spv, a));
      s += delta;
      if (s >= best) { best = s; besti = q; }
      fcnt -= 1.0f;
    }
  } else {
    const float* spg = spos + ((size_t)c << 14);
    for (int q = P - 1; q >= 0; --q) {
      float spv = spg[q];
      float r = __builtin_amdgcn_rcpf(fcnt);
      float delta = fmaf(invP, r, fmaf(-coef, spv, a));
      s += delta;
      if (s >= best) { best = s; besti = q; }
      fcnt -= 1.0f;
    }
  }
  aopt[(c << 9) + ta] = (unsigned)(besti + 1);
}

__global__ void k_optB(const unsigned* __restrict__ counts, const float* __restrict__ spos,
                       const float* __restrict__ sneg, const unsigned* __restrict__ aopt,
                       unsigned* __restrict__ hist, double* __restrict__ accS,
                       double* __restrict__ accV) {
  int c = blockIdx.y;
  int P = (int)counts[c];
  int N = C_ITEMS - P;
  if (P == 0 || N == 0) return;
  int tid = threadIdx.x;
  int j0 = blockIdx.x * 256 + tid;
  bool active = (j0 < N);
  __shared__ float sp[SCAP];
  __shared__ unsigned lh[HCAP];
  __shared__ double red[256];
  int stageN = (P <= SCAP) ? P : 0;
  int zn = (P + 2 <= HCAP) ? (P + 2) : 0;
  for (int t = tid; t < stageN; t += 256) sp[t] = spos[(c << 14) + t];
  for (int t = tid; t < zn; t += 256) lh[t] = 0u;
  __syncthreads();
  int opt = P + 1;
  float v = 0.0f;
  if (active) {
    v = sneg[(c << 14) + j0];
    int g = j0 >> ABITS;
    int hiA = (int)aopt[(c << 9) + g];
    if ((j0 & (ASTEP - 1)) == 0) {
      opt = hiA;
    } else {
      int loA = (int)aopt[(c << 9) + g + 1];
      int hi = min(hiA + 2, P + 1);
      int lo = max(loA - 2, 1);
      float invP = 1.0f / (float)P;
      float coef = 2.0f / ((float)P * (float)N);
      float a = coef * v;
      float s = 0.0f, best = 0.0f;
      int bestr = hi;
      float fcnt = (float)(j0 + hi);
      if (P <= SCAP) {
        for (int k = hi - 1; k >= lo; --k) {
          float spv = sp[k - 1];
          float r = __builtin_amdgcn_rcpf(fcnt);
          float delta = fmaf(invP, r, fmaf(-coef, spv, a));
          s += delta;
          if (s >= best) { best = s; bestr = k; }
          fcnt -= 1.0f;
        }
      } else {
        const float* spg = spos + ((size_t)c << 14);
        for (int k = hi - 1; k >= lo; --k) {
          float spv = spg[k - 1];
          float r = __builtin_amdgcn_rcpf(fcnt);
          float delta = fmaf(invP, r, fmaf(-coef, spv, a));
          s += delta;
          if (s >= best) { best = s; bestr = k; }
          fcnt -= 1.0f;
        }
      }
      opt = bestr;
    }
  }
  if (P + 2 <= HCAP) {
    if (active) atomicAdd(&lh[opt], 1u);
    __syncthreads();
    for (int t = tid; t < P + 2; t += 256)
      if (lh[t]) atomicAdd(&hist[c * HSTRIDE + t], lh[t]);
  } else {
    if (active) atomicAdd(&hist[c * HSTRIDE + opt], 1u);
  }
  double cm = active ? (double)(P + 2 - 2 * opt) * (double)v : 0.0;
  double sv = active ? (double)v : 0.0;
  red[tid] = cm; __syncthreads();
  for (int sh = 128; sh > 0; sh >>= 1) { if (tid < sh) red[tid] += red[tid + sh]; __syncthreads(); }
  if (tid == 0) atomicAdd(&accS[c], red[0]);
  __syncthreads();
  red[tid] = sv; __syncthreads();
  for (int sh = 128; sh > 0; sh >>= 1) { if (tid < sh) red[tid] += red[tid + sh]; __syncthreads(); }
  if (tid == 0) atomicAdd(&accV[c], red[0]);
}

__global__ void k_fin(const unsigned* __restrict__ counts, const unsigned* __restrict__ hist,
                      const float* __restrict__ spos, const double* __restrict__ accS,
                      const double* __restrict__ accV, double* __restrict__ total,
                      unsigned* __restrict__ done, float* __restrict__ out) {
  int c = blockIdx.x;
  int tid = threadIdx.x;
  int P = (int)counts[c];
  int N = C_ITEMS - P;
  __shared__ unsigned sc[256];
  __shared__ double red[256];
  double lc = 0.0;
  if (P > 0 && N > 0) {
    const unsigned* h = hist + c * HSTRIDE;
    int M = P + 1;
    int L = (M + 255) / 256;
    int o0 = 1 + tid * L;
    int o1 = min(o0 + L, P + 2);
    unsigned part = 0;
    for (int o = o0; o < o1; ++o) part += h[o];
    sc[tid] = part;
    __syncthreads();
    if (tid == 0) {
      unsigned runp = 0;
      for (int t = 0; t < 256; ++t) { unsigned tmp = sc[t]; sc[t] = runp; runp += tmp; }
    }
    __syncthreads();
    unsigned run = sc[tid];
    double a1 = 0.0, a2 = 0.0, a3 = 0.0;
    for (int o = o0; o < o1; ++o) {
      run += h[o];
      if (o <= P) {
        int k0 = o - 1;
        double rp = 1.0 + (double)run;
        double spv = (double)spos[(c << 14) + k0];
        a1 += (double)(k0 + 1) / ((double)k0 + rp);
        a2 += spv * ((double)N + 2.0 - 2.0 * rp);
        a3 += spv;
      }
    }
    red[tid] = a1; __syncthreads();
    for (int s = 128; s > 0; s >>= 1) { if (tid < s) red[tid] += red[tid + s]; __syncthreads(); }
    double r1 = red[0]; __syncthreads();
    red[tid] = a2; __syncthreads();
    for (int s = 128; s > 0; s >>= 1) { if (tid < s) red[tid] += red[tid + s]; __syncthreads(); }
    double r2 = red[0]; __syncthreads();
    red[tid] = a3; __syncthreads();
    for (int s = 128; s > 0; s >>= 1) { if (tid < s) red[tid] += red[tid + s]; __syncthreads(); }
    double r3 = red[0];
    if (tid == 0) {
      double Pd = (double)P, Nd = (double)N;
      double FR  = r2 + accS[c];
      double FRs = Nd * r3 - Pd * accV[c];
      lc = (1.0 - r1 / Pd) + (FR - FRs) / (Pd * Nd);
    }
  }
  if (tid == 0) {
    if (P > 0 && N > 0) atomicAdd(total, lc);
    __threadfence();
    unsigned d = atomicAdd(done, 1u);
    if (d == NCLS - 1) {
      double t = atomicAdd(total, 0.0);
      out[0] = (float)(t / (double)NCLS);
    }
  }
}

extern "C" void kernel_launch(void* const* d_in, const int* in_sizes, int n_in,
                              void* d_out, int out_size, void* d_ws, size_t ws_size,
                              hipStream_t stream) {
  (void)in_sizes; (void)n_in; (void)out_size; (void)ws_size;
  const float* scores = (const float*)d_in[0];
  const int* labels = (const int*)d_in[1];
  float* out = (float*)d_out;
  char* ws = (char*)d_ws;

  // ---- primary: single cooperative kernel (9 phases, 1 dispatch) ----
  void* args[] = { (void*)&scores, (void*)&labels, (void*)&ws, (void*)&out };
  hipError_t e = hipLaunchCooperativeKernel((const void*)k_all, dim3(GRID), dim3(BLK),
                                            args, 0, stream);
  if (e == hipSuccess) return;

  // ---- fallback: validated R9 multi-kernel pipeline ----
  float* col      = (float*)(ws + OFF_COL);
  float* spos     = (float*)(ws + OFF_SPOS);
  float* sneg     = (float*)(ws + OFF_SNEG);
  unsigned* pack  = (unsigned*)(ws + OFF_PACK);
  unsigned* hist  = (unsigned*)(ws + OFF_HIST);
  unsigned* done  = (unsigned*)(ws + OFF_CNT);
  double* accS    = (double*)(ws + OFF_ACCS);
  double* accV    = (double*)(ws + OFF_ACCV);
  double* total   = (double*)(ws + OFF_TOT);
  unsigned* pcnt  = (unsigned*)(ws + OFF_PC);
  unsigned* h1    = (unsigned*)(ws + OFF_H1);
  unsigned long long* ppk = (unsigned long long*)(ws + OFF_PPK);
  unsigned* aopt  = (unsigned*)(ws + OFF_PPK);

  int zn = (int)(ZERO_BYTES / 4);
  k_zero<<<1024, 256, 0, stream>>>(hist, zn);
  k_prep<<<1024, 256, 0, stream>>>(scores, labels, col, h1);
  k_posc<<<64, 256, 0, stream>>>(scores, labels, pcnt, ppk);
  k_mid<<<32, 1024, 0, stream>>>(h1, col, pcnt, ppk, spos);
  k_scatter<<<1024, 256, 0, stream>>>(col, labels, h1, pack);
  k_rankfine<<<1024, 256, 0, stream>>>(col, labels, h1, pack, sneg);
  k_anchor<<<dim3(5, NCLS), 64, 0, stream>>>(pcnt, spos, sneg, aopt);
  k_optB<<<dim3(64, NCLS), 256, 0, stream>>>(pcnt, spos, sneg, aopt, hist, accS, accV);
  k_fin<<<NCLS, 256, 0, stream>>>(pcnt, hist, spos, accS, accV, total, done, out);
}

// Round 11
// 293.062 us; speedup vs baseline: 3.1587x; 3.1587x over previous
//
#include <hip/hip_runtime.h>
#include <stdint.h>

#define C_ITEMS 16384
#define NCLS 16
#define HSTRIDE 16386   // AP hist entries per class (opt in [1, P+1])
#define NB 65536        // negative sort buckets per class (ordkey >> 16)
#define BSH 16

// ---- workspace layout (bytes) ----
// col[0,1M) spos[1M,2M) sneg[2M,3M) pack[3M,4M) hist+scalars+h1[4M,~9.44M) ppk[10M,12M)
static const size_t OFF_COL  = 0;
static const size_t OFF_SPOS = 1u << 20;
static const size_t OFF_SNEG = 2u << 20;
static const size_t OFF_PACK = 3u << 20;
static const size_t OFF_HIST = 4u << 20;
static const size_t OFF_CNT  = OFF_HIST + (size_t)NCLS * HSTRIDE * 4;  // done counter
static const size_t OFF_ACCS = OFF_CNT + 64;
static const size_t OFF_ACCV = OFF_ACCS + 128;
static const size_t OFF_TOT  = OFF_ACCV + 128;
static const size_t OFF_PC   = OFF_TOT + 8;    // 16 u32 positive counters (= per-class P)
static const size_t OFF_H1   = (OFF_PC + 64 + 255) & ~(size_t)255;     // 16*65536 u32 (4 MB)
static const size_t ZERO_END = OFF_H1 + ((size_t)NCLS * NB * 4);
static const size_t ZERO_BYTES = ZERO_END - OFF_HIST;                  // ~5.25 MB contiguous
static const size_t OFF_PPK  = 10u << 20;      // 16*16384 u64 positive keys

__device__ __forceinline__ unsigned ordkey(float f) {
  unsigned b = __float_as_uint(f);
  return (b & 0x80000000u) ? ~b : (b | 0x80000000u);   // monotone float->uint
}

__global__ void k_zero(unsigned* __restrict__ p, int n) {
  int stride = gridDim.x * blockDim.x;
  for (int t = blockIdx.x * blockDim.x + threadIdx.x; t < n; t += stride) p[t] = 0u;
}

// ---- fused: transpose + negative bucket histogram (all 1024 blocks, wide)
//      + positive two-level collect (blocks 0-63 extra duty) ----
// Histogram/transpose mapping identical to validated k_prep; posc branch is the
// validated k_posc verbatim (block-uniform branch; ppk order changes are
// permutation-invariant downstream).
__global__ void k_prep2(const float* __restrict__ scores, const int* __restrict__ labels,
                        float* __restrict__ col, unsigned* __restrict__ h1,
                        unsigned* __restrict__ pcnt, unsigned long long* __restrict__ ppk) {
  int t = blockIdx.x * 256 + threadIdx.x;      // 0..262143
  float v = scores[t];
  int i = t >> 4, c = t & 15;
  col[(c << 14) | i] = v;
  if (labels[i] != c)
    atomicAdd(&h1[(c << 16) + (ordkey(v) >> BSH)], 1u);
  if (blockIdx.x < 64) {
    __shared__ unsigned lc[NCLS];
    __shared__ unsigned base[NCLS];
    int tid = threadIdx.x;
    if (tid < NCLS) lc[tid] = 0;
    __syncthreads();
    int ii = blockIdx.x * 256 + tid;   // 0..16383
    int cc = labels[ii] & 15;
    float vv = scores[ii * NCLS + cc];
    unsigned loc = atomicAdd(&lc[cc], 1u);
    __syncthreads();
    if (tid < NCLS) base[tid] = lc[tid] ? atomicAdd(&pcnt[tid], lc[tid]) : 0u;
    __syncthreads();
    ppk[(cc << 14) + base[cc] + loc] = ((unsigned long long)(~ordkey(vv)) << 32) | (unsigned)ii;
  }
}

// ---- fused per-class sort chain + positive rank (32 blocks x 1024) ----
// Blocks 0-15: class b is ENTIRELY block-local after k_prep2 -> scan, scatter,
// rankfine chained with block barriers only (no grid sync needed).
// Blocks 16-31: positive rank for class (b-16) -- unchanged from validated k_mid.
#define PCAP 2048
__global__ __launch_bounds__(1024) void k_mid2(
    unsigned* __restrict__ h1, const float* __restrict__ col,
    const int* __restrict__ labels, unsigned* __restrict__ pack,
    float* __restrict__ sneg, const unsigned* __restrict__ pcnt,
    const unsigned long long* __restrict__ ppk, float* __restrict__ spos) {
  int b = blockIdx.x;
  int tid = threadIdx.x;
  __shared__ unsigned part[1024];
  __shared__ unsigned long long pk[PCAP];
  if (b < NCLS) {
    int c = b;
    unsigned* h = h1 + ((size_t)c << 16);
    // --- exclusive scan over 64K buckets (validated ladder) ---
    unsigned base = (unsigned)tid << 6;
    unsigned s = 0;
    for (int q = 0; q < 64; ++q) s += h[base + q];
    part[tid] = s;
    __syncthreads();
    for (int off = 1; off < 1024; off <<= 1) {
      unsigned v = (tid >= off) ? part[tid - off] : 0u;
      __syncthreads();
      part[tid] += v;
      __syncthreads();
    }
    unsigned running = part[tid] - s;
    for (int q = 0; q < 64; ++q) {
      unsigned tmp = h[base + q];
      h[base + q] = running;
      running += tmp;
    }
    __threadfence_block();
    __syncthreads();
    // --- scatter class-c negatives (h[x] becomes bucket END) ---
    for (int i = tid; i < C_ITEMS; i += 1024)
      if (labels[i] != c) {
        unsigned k = ordkey(col[(c << 14) + i]);
        unsigned p = atomicAdd(&h[k >> BSH], 1u);
        pack[(c << 14) + p] = (k << 16) | (unsigned)i;   // low16 key + idx: unique
      }
    __threadfence_block();
    __syncthreads();
    // --- rankfine -> sneg by ascending rank (validated math) ---
    for (int i = tid; i < C_ITEMS; i += 1024)
      if (labels[i] != c) {
        float v = col[(c << 14) + i];
        unsigned k = ordkey(v);
        unsigned bb = k >> BSH;
        unsigned start = bb ? h[bb - 1] : 0u;
        unsigned end = h[bb];
        unsigned mine = (k << 16) | (unsigned)i;
        const unsigned* pk2 = pack + (c << 14);
        unsigned cnt = start;
        for (unsigned q = start; q < end; ++q) cnt += (pk2[q] < mine) ? 1u : 0u;
        sneg[(c << 14) + (int)cnt] = v;
      }
  } else {
    // --- positive rank: keys unique -> count-smaller is permutation-invariant ---
    int c = b - NCLS;
    unsigned P = pcnt[c];
    const unsigned long long* src = ppk + ((size_t)c << 14);
    if (P <= PCAP) {
      for (unsigned t = tid; t < P; t += 1024) pk[t] = src[t];
      __syncthreads();
      for (unsigned q = tid; q < P; q += 1024) {
        unsigned long long k64 = pk[q];
        unsigned cq = 0;
        for (unsigned t = 0; t < P; ++t) cq += (pk[t] < k64) ? 1u : 0u;
        unsigned i = (unsigned)(k64 & 0xFFFFFFFFu);
        spos[(c << 14) + cq] = col[(c << 14) + (int)i];
      }
    } else {  // safety fallback (won't trigger for this input)
      for (unsigned q = tid; q < P; q += 1024) {
        unsigned long long k64 = src[q];
        unsigned cq = 0;
        for (unsigned t = 0; t < P; ++t) cq += (src[t] < k64) ? 1u : 0u;
        unsigned i = (unsigned)(k64 & 0xFFFFFFFFu);
        spos[(c << 14) + cq] = col[(c << 14) + (int)i];
      }
    }
  }
}

// ============================================================================
// opt_j monotone non-increasing in ascending rank j (the property the
// reference's quickselect D&C exploits) => anchors every ASTEP ranks bracket
// every intermediate opt. Each block now computes its OWN 5 bracketing anchors
// (threads 0-4, exact validated serial scans) -- no separate anchor dispatch.
// ============================================================================
#define SCAP 2048
#define HCAP 2048
#define ASTEP 64
#define ABITS 6

__global__ void k_optB2(const unsigned* __restrict__ counts, const float* __restrict__ spos,
                        const float* __restrict__ sneg, unsigned* __restrict__ hist,
                        double* __restrict__ accS, double* __restrict__ accV) {
  int c = blockIdx.y;
  int P = (int)counts[c];
  int N = C_ITEMS - P;
  if (P == 0 || N == 0) return;
  int tid = threadIdx.x;
  int jbase = blockIdx.x * 256;
  int j0 = jbase + tid;
  bool active = (j0 < N);
  __shared__ float sp[SCAP];
  __shared__ unsigned lh[HCAP];
  __shared__ double red[256];
  __shared__ unsigned la[8];          // 5 anchors for this block's j-range
  int stageN = (P <= SCAP) ? P : 0;
  int zn = (P + 2 <= HCAP) ? (P + 2) : 0;
  for (int t = tid; t < stageN; t += 256) sp[t] = spos[(c << 14) + t];
  for (int t = tid; t < zn; t += 256) lh[t] = 0u;
  __syncthreads();
  float invP = 1.0f / (float)P;
  float coef = 2.0f / ((float)P * (float)N);
  // --- anchors t = blockIdx.x*4 + {0..4}, j0a = min(t*64, N-1): exact full scan ---
  if (jbase < N && tid < 5) {
    int j0a = min((blockIdx.x * 4 + tid) * ASTEP, N - 1);
    float v = sneg[(c << 14) + j0a];
    float a = coef * v;
    float fcnt = (float)(j0a + P + 1);
    float s = 0.0f, best = 0.0f;
    int besti = P;
    if (P <= SCAP) {
      for (int q = P - 1; q >= 0; --q) {
        float spv = sp[q];
        float r = __builtin_amdgcn_rcpf(fcnt);
        float delta = fmaf(invP, r, fmaf(-coef, spv, a));
        s += delta;
        if (s >= best) { best = s; besti = q; }
        fcnt -= 1.0f;
      }
    } else {
      const float* spg = spos + ((size_t)c << 14);
      for (int q = P - 1; q >= 0; --q) {
        float spv = spg[q];
        float r = __builtin_amdgcn_rcpf(fcnt);
        float delta = fmaf(invP, r, fmaf(-coef, spv, a));
        s += delta;
        if (s >= best) { best = s; besti = q; }
        fcnt -= 1.0f;
      }
    }
    la[tid] = (unsigned)(besti + 1);
  }
  __syncthreads();
  // --- bracketed argmax (validated math; la replaces global aopt) ---
  int opt = P + 1;
  float v = 0.0f;
  if (active) {
    v = sneg[(c << 14) + j0];
    int gl = (j0 >> ABITS) - blockIdx.x * 4;   // 0..3
    int hiA = (int)la[gl];
    if ((j0 & (ASTEP - 1)) == 0) {
      opt = hiA;                      // anchor rank: exact full-scan value
    } else {
      int loA = (int)la[gl + 1];
      int hi = min(hiA + 2, P + 1);   // +-2 margin absorbs float near-tie wobble
      int lo = max(loA - 2, 1);
      float a = coef * v;
      float s = 0.0f, best = 0.0f;
      int bestr = hi;                 // empty suffix (value 0) candidate at r=hi
      float fcnt = (float)(j0 + hi);  // j0+1+k at k=hi-1
      if (P <= SCAP) {
        for (int k = hi - 1; k >= lo; --k) {
          float spv = sp[k - 1];
          float r = __builtin_amdgcn_rcpf(fcnt);
          float delta = fmaf(invP, r, fmaf(-coef, spv, a));
          s += delta;
          if (s >= best) { best = s; bestr = k; }
          fcnt -= 1.0f;
        }
      } else {
        const float* spg = spos + ((size_t)c << 14);
        for (int k = hi - 1; k >= lo; --k) {
          float spv = spg[k - 1];
          float r = __builtin_amdgcn_rcpf(fcnt);
          float delta = fmaf(invP, r, fmaf(-coef, spv, a));
          s += delta;
          if (s >= best) { best = s; bestr = k; }
          fcnt -= 1.0f;
        }
      }
      opt = bestr;
    }
  }
  if (P + 2 <= HCAP) {
    if (active) atomicAdd(&lh[opt], 1u);
    __syncthreads();
    for (int t = tid; t < P + 2; t += 256)
      if (lh[t]) atomicAdd(&hist[c * HSTRIDE + t], lh[t]);
  } else {
    if (active) atomicAdd(&hist[c * HSTRIDE + opt], 1u);
  }
  double cm = active ? (double)(P + 2 - 2 * opt) * (double)v : 0.0;
  double sv = active ? (double)v : 0.0;
  red[tid] = cm; __syncthreads();
  for (int sh = 128; sh > 0; sh >>= 1) { if (tid < sh) red[tid] += red[tid + sh]; __syncthreads(); }
  if (tid == 0) atomicAdd(&accS[c], red[0]);
  __syncthreads();
  red[tid] = sv; __syncthreads();
  for (int sh = 128; sh > 0; sh >>= 1) { if (tid < sh) red[tid] += red[tid + sh]; __syncthreads(); }
  if (tid == 0) atomicAdd(&accV[c], red[0]);
}

// ---- per-class: prefix-sum hist -> r_plus, plus-side sums, loss, final out ----
__global__ void k_fin(const unsigned* __restrict__ counts, const unsigned* __restrict__ hist,
                      const float* __restrict__ spos, const double* __restrict__ accS,
                      const double* __restrict__ accV, double* __restrict__ total,
                      unsigned* __restrict__ done, float* __restrict__ out) {
  int c = blockIdx.x;
  int tid = threadIdx.x;
  int P = (int)counts[c];
  int N = C_ITEMS - P;
  __shared__ unsigned sc[256];
  __shared__ double red[256];
  double lc = 0.0;
  if (P > 0 && N > 0) {
    const unsigned* h = hist + c * HSTRIDE;
    int M = P + 1;
    int L = (M + 255) / 256;
    int o0 = 1 + tid * L;
    int o1 = min(o0 + L, P + 2);
    unsigned part = 0;
    for (int o = o0; o < o1; ++o) part += h[o];
    sc[tid] = part;
    __syncthreads();
    if (tid == 0) {
      unsigned runp = 0;
      for (int t = 0; t < 256; ++t) { unsigned tmp = sc[t]; sc[t] = runp; runp += tmp; }
    }
    __syncthreads();
    unsigned run = sc[tid];
    double a1 = 0.0, a2 = 0.0, a3 = 0.0;
    for (int o = o0; o < o1; ++o) {
      run += h[o];
      if (o <= P) {
        int k0 = o - 1;
        double rp = 1.0 + (double)run;
        double spv = (double)spos[(c << 14) + k0];
        a1 += (double)(k0 + 1) / ((double)k0 + rp);
        a2 += spv * ((double)N + 2.0 - 2.0 * rp);
        a3 += spv;
      }
    }
    red[tid] = a1; __syncthreads();
    for (int s = 128; s > 0; s >>= 1) { if (tid < s) red[tid] += red[tid + s]; __syncthreads(); }
    double r1 = red[0]; __syncthreads();
    red[tid] = a2; __syncthreads();
    for (int s = 128; s > 0; s >>= 1) { if (tid < s) red[tid] += red[tid + s]; __syncthreads(); }
    double r2 = red[0]; __syncthreads();
    red[tid] = a3; __syncthreads();
    for (int s = 128; s > 0; s >>= 1) { if (tid < s) red[tid] += red[tid + s]; __syncthreads(); }
    double r3 = red[0];
    if (tid == 0) {
      double Pd = (double)P, Nd = (double)N;
      double FR  = r2 + accS[c];
      double FRs = Nd * r3 - Pd * accV[c];
      lc = (1.0 - r1 / Pd) + (FR - FRs) / (Pd * Nd);
    }
  }
  if (tid == 0) {
    if (P > 0 && N > 0) atomicAdd(total, lc);
    __threadfence();
    unsigned d = atomicAdd(done, 1u);
    if (d == NCLS - 1) {
      double t = atomicAdd(total, 0.0);  // device-scope RMW: coherent final value
      out[0] = (float)(t / (double)NCLS);
    }
  }
}

extern "C" void kernel_launch(void* const* d_in, const int* in_sizes, int n_in,
                              void* d_out, int out_size, void* d_ws, size_t ws_size,
                              hipStream_t stream) {
  (void)in_sizes; (void)n_in; (void)out_size; (void)ws_size;
  const float* scores = (const float*)d_in[0];
  const int* labels = (const int*)d_in[1];
  float* out = (float*)d_out;
  char* ws = (char*)d_ws;
  float* col      = (float*)(ws + OFF_COL);
  float* spos     = (float*)(ws + OFF_SPOS);
  float* sneg     = (float*)(ws + OFF_SNEG);
  unsigned* pack  = (unsigned*)(ws + OFF_PACK);
  unsigned* hist  = (unsigned*)(ws + OFF_HIST);
  unsigned* done  = (unsigned*)(ws + OFF_CNT);
  double* accS    = (double*)(ws + OFF_ACCS);
  double* accV    = (double*)(ws + OFF_ACCV);
  double* total   = (double*)(ws + OFF_TOT);
  unsigned* pcnt  = (unsigned*)(ws + OFF_PC);   // per-class P counts
  unsigned* h1    = (unsigned*)(ws + OFF_H1);
  unsigned long long* ppk = (unsigned long long*)(ws + OFF_PPK);

  int zn = (int)(ZERO_BYTES / 4);
  k_zero<<<1024, 256, 0, stream>>>(hist, zn);   // zeroes hist..h1 (contiguous ~5.25 MB)
  k_prep2<<<1024, 256, 0, stream>>>(scores, labels, col, h1, pcnt, ppk);
  k_mid2<<<32, 1024, 0, stream>>>(h1, col, labels, pack, sneg, pcnt, ppk, spos);
  k_optB2<<<dim3(64, NCLS), 256, 0, stream>>>(pcnt, spos, sneg, hist, accS, accV);
  k_fin<<<NCLS, 256, 0, stream>>>(pcnt, hist, spos, accS, accV, total, done, out);
}

// Round 12
// 223.047 us; speedup vs baseline: 4.1503x; 1.3139x over previous
//
#include <hip/hip_runtime.h>
#include <stdint.h>

#define C_ITEMS 16384
#define NCLS 16
#define HSTRIDE 16386   // AP hist entries per class (opt in [1, P+1])
#define NB 65536        // negative sort buckets per class (ordkey >> 16)
#define BSH 16

// ---- workspace layout (bytes) ----
// col[0,1M) spos[1M,2M) sneg[2M,3M) pack[3M,4M) hist+scalars+h1[4M,~9.44M) ppk[10M,12M)
static const size_t OFF_COL  = 0;
static const size_t OFF_SPOS = 1u << 20;
static const size_t OFF_SNEG = 2u << 20;
static const size_t OFF_PACK = 3u << 20;
static const size_t OFF_HIST = 4u << 20;
static const size_t OFF_CNT  = OFF_HIST + (size_t)NCLS * HSTRIDE * 4;  // done counter
static const size_t OFF_ACCS = OFF_CNT + 64;
static const size_t OFF_ACCV = OFF_ACCS + 128;
static const size_t OFF_TOT  = OFF_ACCV + 128;
static const size_t OFF_PC   = OFF_TOT + 8;    // 16 u32 positive counters (= per-class P)
static const size_t OFF_H1   = (OFF_PC + 64 + 255) & ~(size_t)255;     // 16*65536 u32 (4 MB)
static const size_t ZERO_END = OFF_H1 + ((size_t)NCLS * NB * 4);
static const size_t ZERO_BYTES = ZERO_END - OFF_HIST;                  // ~5.25 MB contiguous
static const size_t OFF_PPK  = 10u << 20;      // 16*16384 u64 positive keys

__device__ __forceinline__ unsigned ordkey(float f) {
  unsigned b = __float_as_uint(f);
  return (b & 0x80000000u) ? ~b : (b | 0x80000000u);   // monotone float->uint
}

__global__ void k_zero(unsigned* __restrict__ p, int n) {
  int stride = gridDim.x * blockDim.x;
  for (int t = blockIdx.x * blockDim.x + threadIdx.x; t < n; t += stride) p[t] = 0u;
}

// ---- fused: transpose + negative bucket histogram (all 1024 blocks, wide)
//      + positive two-level collect (blocks 0-63 extra duty) [R11-validated] ----
__global__ void k_prep2(const float* __restrict__ scores, const int* __restrict__ labels,
                        float* __restrict__ col, unsigned* __restrict__ h1,
                        unsigned* __restrict__ pcnt, unsigned long long* __restrict__ ppk) {
  int t = blockIdx.x * 256 + threadIdx.x;      // 0..262143
  float v = scores[t];
  int i = t >> 4, c = t & 15;
  col[(c << 14) | i] = v;
  if (labels[i] != c)
    atomicAdd(&h1[(c << 16) + (ordkey(v) >> BSH)], 1u);
  if (blockIdx.x < 64) {
    __shared__ unsigned lc[NCLS];
    __shared__ unsigned base[NCLS];
    int tid = threadIdx.x;
    if (tid < NCLS) lc[tid] = 0;
    __syncthreads();
    int ii = blockIdx.x * 256 + tid;   // 0..16383
    int cc = labels[ii] & 15;
    float vv = scores[ii * NCLS + cc];
    unsigned loc = atomicAdd(&lc[cc], 1u);
    __syncthreads();
    if (tid < NCLS) base[tid] = lc[tid] ? atomicAdd(&pcnt[tid], lc[tid]) : 0u;
    __syncthreads();
    ppk[(cc << 14) + base[cc] + loc] = ((unsigned long long)(~ordkey(vv)) << 32) | (unsigned)ii;
  }
}

// ---- merged: blocks 0-15 = per-class 64K-bucket exclusive scan (1024 thr);
//      blocks 16-31 = positive rank (1 block/class, 1024 thr) [R9-validated] ----
#define PCAP 2048
__global__ __launch_bounds__(1024) void k_mid(
    unsigned* __restrict__ h1, const float* __restrict__ col,
    const unsigned* __restrict__ pcnt, const unsigned long long* __restrict__ ppk,
    float* __restrict__ spos) {
  int b = blockIdx.x;
  int tid = threadIdx.x;
  __shared__ unsigned part[1024];
  __shared__ unsigned long long pk[PCAP];
  if (b < NCLS) {
    unsigned* h = h1 + ((size_t)b << 16);
    unsigned base = (unsigned)tid << 6;
    unsigned s = 0;
    for (int q = 0; q < 64; ++q) s += h[base + q];
    part[tid] = s;
    __syncthreads();
    for (int off = 1; off < 1024; off <<= 1) {
      unsigned v = (tid >= off) ? part[tid - off] : 0u;
      __syncthreads();
      part[tid] += v;
      __syncthreads();
    }
    unsigned running = part[tid] - s;   // exclusive prefix of this thread's chunk
    for (int q = 0; q < 64; ++q) {
      unsigned tmp = h[base + q];
      h[base + q] = running;
      running += tmp;
    }
  } else {
    // positive rank: keys unique -> count-smaller is permutation-invariant
    int c = b - NCLS;
    unsigned P = pcnt[c];
    const unsigned long long* src = ppk + ((size_t)c << 14);
    if (P <= PCAP) {
      for (unsigned t = tid; t < P; t += 1024) pk[t] = src[t];
      __syncthreads();
      for (unsigned q = tid; q < P; q += 1024) {
        unsigned long long k64 = pk[q];
        unsigned cq = 0;
        for (unsigned t = 0; t < P; ++t) cq += (pk[t] < k64) ? 1u : 0u;
        unsigned i = (unsigned)(k64 & 0xFFFFFFFFu);
        spos[(c << 14) + cq] = col[(c << 14) + (int)i];
      }
    } else {  // safety fallback (won't trigger for this input)
      for (unsigned q = tid; q < P; q += 1024) {
        unsigned long long k64 = src[q];
        unsigned cq = 0;
        for (unsigned t = 0; t < P; ++t) cq += (src[t] < k64) ? 1u : 0u;
        unsigned i = (unsigned)(k64 & 0xFFFFFFFFu);
        spos[(c << 14) + cq] = col[(c << 14) + (int)i];
      }
    }
  }
}

// ---- scatter negatives (WIDE 1024 blocks; h1[b] becomes bucket END) ----
__global__ void k_scatter(const float* __restrict__ col, const int* __restrict__ labels,
                          unsigned* __restrict__ h1, unsigned* __restrict__ pack) {
  int t = blockIdx.x * 256 + threadIdx.x;
  int c = t >> 14, i = t & 16383;
  if (labels[i] != c) {
    unsigned k = ordkey(col[t]);
    unsigned p = atomicAdd(&h1[(c << 16) + (k >> BSH)], 1u);
    pack[(c << 14) + p] = (k << 16) | (unsigned)i;   // low16 key + idx: unique stable
  }
}

// ---- final rank (WIDE; bucket start + count-smaller in bucket) -> sneg ----
__global__ void k_rankfine(const float* __restrict__ col, const int* __restrict__ labels,
                           const unsigned* __restrict__ h1, const unsigned* __restrict__ pack,
                           float* __restrict__ sneg) {
  int t = blockIdx.x * 256 + threadIdx.x;
  int c = t >> 14, i = t & 16383;
  if (labels[i] != c) {
    float v = col[t];
    unsigned k = ordkey(v);
    unsigned b = k >> BSH;
    const unsigned* hb = h1 + ((size_t)c << 16);
    unsigned start = b ? hb[b - 1] : 0u;   // after scatter: hb[x] = end of bucket x
    unsigned end = hb[b];
    unsigned mine = (k << 16) | (unsigned)i;
    const unsigned* pk = pack + (c << 14);
    unsigned cnt = start;
    for (unsigned q = start; q < end; ++q) cnt += (pk[q] < mine) ? 1u : 0u;
    sneg[(c << 14) + (int)cnt] = v;        // cnt = 0-based ascending rank (unique)
  }
}

// ============================================================================
// opt_j monotone non-increasing in ascending rank j (the property the
// reference's quickselect D&C exploits) => anchors every ASTEP ranks bracket
// every intermediate opt. Each block computes its OWN 5 bracketing anchors
// (threads 0-4, exact validated serial scans) [R11-validated].
// ============================================================================
#define SCAP 2048
#define HCAP 2048
#define ASTEP 64
#define ABITS 6

__global__ void k_optB2(const unsigned* __restrict__ counts, const float* __restrict__ spos,
                        const float* __restrict__ sneg, unsigned* __restrict__ hist,
                        double* __restrict__ accS, double* __restrict__ accV) {
  int c = blockIdx.y;
  int P = (int)counts[c];
  int N = C_ITEMS - P;
  if (P == 0 || N == 0) return;
  int tid = threadIdx.x;
  int jbase = blockIdx.x * 256;
  int j0 = jbase + tid;
  bool active = (j0 < N);
  __shared__ float sp[SCAP];
  __shared__ unsigned lh[HCAP];
  __shared__ double red[256];
  __shared__ unsigned la[8];          // 5 anchors for this block's j-range
  int stageN = (P <= SCAP) ? P : 0;
  int zn = (P + 2 <= HCAP) ? (P + 2) : 0;
  for (int t = tid; t < stageN; t += 256) sp[t] = spos[(c << 14) + t];
  for (int t = tid; t < zn; t += 256) lh[t] = 0u;
  __syncthreads();
  float invP = 1.0f / (float)P;
  float coef = 2.0f / ((float)P * (float)N);
  // --- anchors t = blockIdx.x*4 + {0..4}, j0a = min(t*64, N-1): exact full scan ---
  if (jbase < N && tid < 5) {
    int j0a = min((blockIdx.x * 4 + tid) * ASTEP, N - 1);
    float v = sneg[(c << 14) + j0a];
    float a = coef * v;
    float fcnt = (float)(j0a + P + 1);
    float s = 0.0f, best = 0.0f;
    int besti = P;
    if (P <= SCAP) {
      for (int q = P - 1; q >= 0; --q) {
        float spv = sp[q];
        float r = __builtin_amdgcn_rcpf(fcnt);
        float delta = fmaf(invP, r, fmaf(-coef, spv, a));
        s += delta;
        if (s >= best) { best = s; besti = q; }
        fcnt -= 1.0f;
      }
    } else {
      const float* spg = spos + ((size_t)c << 14);
      for (int q = P - 1; q >= 0; --q) {
        float spv = spg[q];
        float r = __builtin_amdgcn_rcpf(fcnt);
        float delta = fmaf(invP, r, fmaf(-coef, spv, a));
        s += delta;
        if (s >= best) { best = s; besti = q; }
        fcnt -= 1.0f;
      }
    }
    la[tid] = (unsigned)(besti + 1);
  }
  __syncthreads();
  // --- bracketed argmax (validated math; la replaces global aopt) ---
  int opt = P + 1;
  float v = 0.0f;
  if (active) {
    v = sneg[(c << 14) + j0];
    int gl = (j0 >> ABITS) - blockIdx.x * 4;   // 0..3
    int hiA = (int)la[gl];
    if ((j0 & (ASTEP - 1)) == 0) {
      opt = hiA;                      // anchor rank: exact full-scan value
    } else {
      int loA = (int)la[gl + 1];
      int hi = min(hiA + 2, P + 1);   // +-2 margin absorbs float near-tie wobble
      int lo = max(loA - 2, 1);
      float a = coef * v;
      float s = 0.0f, best = 0.0f;
      int bestr = hi;                 // empty suffix (value 0) candidate at r=hi
      float fcnt = (float)(j0 + hi);  // j0+1+k at k=hi-1
      if (P <= SCAP) {
        for (int k = hi - 1; k >= lo; --k) {
          float spv = sp[k - 1];
          float r = __builtin_amdgcn_rcpf(fcnt);
          float delta = fmaf(invP, r, fmaf(-coef, spv, a));
          s += delta;
          if (s >= best) { best = s; bestr = k; }
          fcnt -= 1.0f;
        }
      } else {
        const float* spg = spos + ((size_t)c << 14);
        for (int k = hi - 1; k >= lo; --k) {
          float spv = spg[k - 1];
          float r = __builtin_amdgcn_rcpf(fcnt);
          float delta = fmaf(invP, r, fmaf(-coef, spv, a));
          s += delta;
          if (s >= best) { best = s; bestr = k; }
          fcnt -= 1.0f;
        }
      }
      opt = bestr;
    }
  }
  if (P + 2 <= HCAP) {
    if (active) atomicAdd(&lh[opt], 1u);
    __syncthreads();
    for (int t = tid; t < P + 2; t += 256)
      if (lh[t]) atomicAdd(&hist[c * HSTRIDE + t], lh[t]);
  } else {
    if (active) atomicAdd(&hist[c * HSTRIDE + opt], 1u);
  }
  double cm = active ? (double)(P + 2 - 2 * opt) * (double)v : 0.0;
  double sv = active ? (double)v : 0.0;
  red[tid] = cm; __syncthreads();
  for (int sh = 128; sh > 0; sh >>= 1) { if (tid < sh) red[tid] += red[tid + sh]; __syncthreads(); }
  if (tid == 0) atomicAdd(&accS[c], red[0]);
  __syncthreads();
  red[tid] = sv; __syncthreads();
  for (int sh = 128; sh > 0; sh >>= 1) { if (tid < sh) red[tid] += red[tid + sh]; __syncthreads(); }
  if (tid == 0) atomicAdd(&accV[c], red[0]);
}

// ---- per-class: prefix-sum hist -> r_plus, plus-side sums, loss, final out ----
__global__ void k_fin(const unsigned* __restrict__ counts, const unsigned* __restrict__ hist,
                      const float* __restrict__ spos, const double* __restrict__ accS,
                      const double* __restrict__ accV, double* __restrict__ total,
                      unsigned* __restrict__ done, float* __restrict__ out) {
  int c = blockIdx.x;
  int tid = threadIdx.x;
  int P = (int)counts[c];
  int N = C_ITEMS - P;
  __shared__ unsigned sc[256];
  __shared__ double red[256];
  double lc = 0.0;
  if (P > 0 && N > 0) {
    const unsigned* h = hist + c * HSTRIDE;
    int M = P + 1;
    int L = (M + 255) / 256;
    int o0 = 1 + tid * L;
    int o1 = min(o0 + L, P + 2);
    unsigned part = 0;
    for (int o = o0; o < o1; ++o) part += h[o];
    sc[tid] = part;
    __syncthreads();
    if (tid == 0) {
      unsigned runp = 0;
      for (int t = 0; t < 256; ++t) { unsigned tmp = sc[t]; sc[t] = runp; runp += tmp; }
    }
    __syncthreads();
    unsigned run = sc[tid];
    double a1 = 0.0, a2 = 0.0, a3 = 0.0;
    for (int o = o0; o < o1; ++o) {
      run += h[o];
      if (o <= P) {
        int k0 = o - 1;
        double rp = 1.0 + (double)run;
        double spv = (double)spos[(c << 14) + k0];
        a1 += (double)(k0 + 1) / ((double)k0 + rp);
        a2 += spv * ((double)N + 2.0 - 2.0 * rp);
        a3 += spv;
      }
    }
    red[tid] = a1; __syncthreads();
    for (int s = 128; s > 0; s >>= 1) { if (tid < s) red[tid] += red[tid + s]; __syncthreads(); }
    double r1 = red[0]; __syncthreads();
    red[tid] = a2; __syncthreads();
    for (int s = 128; s > 0; s >>= 1) { if (tid < s) red[tid] += red[tid + s]; __syncthreads(); }
    double r2 = red[0]; __syncthreads();
    red[tid] = a3; __syncthreads();
    for (int s = 128; s > 0; s >>= 1) { if (tid < s) red[tid] += red[tid + s]; __syncthreads(); }
    double r3 = red[0];
    if (tid == 0) {
      double Pd = (double)P, Nd = (double)N;
      double FR  = r2 + accS[c];
      double FRs = Nd * r3 - Pd * accV[c];
      lc = (1.0 - r1 / Pd) + (FR - FRs) / (Pd * Nd);
    }
  }
  if (tid == 0) {
    if (P > 0 && N > 0) atomicAdd(total, lc);
    __threadfence();
    unsigned d = atomicAdd(done, 1u);
    if (d == NCLS - 1) {
      double t = atomicAdd(total, 0.0);  // device-scope RMW: coherent final value
      out[0] = (float)(t / (double)NCLS);
    }
  }
}

extern "C" void kernel_launch(void* const* d_in, const int* in_sizes, int n_in,
                              void* d_out, int out_size, void* d_ws, size_t ws_size,
                              hipStream_t stream) {
  (void)in_sizes; (void)n_in; (void)out_size; (void)ws_size;
  const float* scores = (const float*)d_in[0];
  const int* labels = (const int*)d_in[1];
  float* out = (float*)d_out;
  char* ws = (char*)d_ws;
  float* col      = (float*)(ws + OFF_COL);
  float* spos     = (float*)(ws + OFF_SPOS);
  float* sneg     = (float*)(ws + OFF_SNEG);
  unsigned* pack  = (unsigned*)(ws + OFF_PACK);
  unsigned* hist  = (unsigned*)(ws + OFF_HIST);
  unsigned* done  = (unsigned*)(ws + OFF_CNT);
  double* accS    = (double*)(ws + OFF_ACCS);
  double* accV    = (double*)(ws + OFF_ACCV);
  double* total   = (double*)(ws + OFF_TOT);
  unsigned* pcnt  = (unsigned*)(ws + OFF_PC);   // per-class P counts
  unsigned* h1    = (unsigned*)(ws + OFF_H1);
  unsigned long long* ppk = (unsigned long long*)(ws + OFF_PPK);

  int zn = (int)(ZERO_BYTES / 4);
  k_zero<<<1024, 256, 0, stream>>>(hist, zn);   // zeroes hist..h1 (contiguous ~5.25 MB)
  k_prep2<<<1024, 256, 0, stream>>>(scores, labels, col, h1, pcnt, ppk);
  k_mid<<<32, 1024, 0, stream>>>(h1, col, pcnt, ppk, spos);
  k_scatter<<<1024, 256, 0, stream>>>(col, labels, h1, pack);
  k_rankfine<<<1024, 256, 0, stream>>>(col, labels, h1, pack, sneg);
  k_optB2<<<dim3(64, NCLS), 256, 0, stream>>>(pcnt, spos, sneg, hist, accS, accV);
  k_fin<<<NCLS, 256, 0, stream>>>(pcnt, hist, spos, accS, accV, total, done, out);
}

// Round 13
// 196.223 us; speedup vs baseline: 4.7176x; 1.1367x over previous
//
#include <hip/hip_runtime.h>
#include <stdint.h>

#define C_ITEMS 16384
#define NCLS 16
#define HSTRIDE 16386   // AP hist entries per class (opt in [1, P+1])
#define NB 65536        // negative sort buckets per class (ordkey >> 16)
#define BSH 16

// ---- workspace layout (bytes) ----
// col[0,1M) spos[1M,2M) sneg[2M,3M) pack[3M,4M) hist+scalars+h1[4M,~9.44M) ppk[10M,12M)
static const size_t OFF_COL  = 0;
static const size_t OFF_SPOS = 1u << 20;
static const size_t OFF_SNEG = 2u << 20;
static const size_t OFF_PACK = 3u << 20;
static const size_t OFF_HIST = 4u << 20;
static const size_t OFF_CNT  = OFF_HIST + (size_t)NCLS * HSTRIDE * 4;  // done counter
static const size_t OFF_ACCS = OFF_CNT + 64;
static const size_t OFF_ACCV = OFF_ACCS + 128;
static const size_t OFF_TOT  = OFF_ACCV + 128;
static const size_t OFF_PC   = OFF_TOT + 8;    // 16 u32 positive counters (= per-class P)
static const size_t OFF_H1   = (OFF_PC + 64 + 255) & ~(size_t)255;     // 16*65536 u32 (4 MB)
static const size_t ZERO_END = OFF_H1 + ((size_t)NCLS * NB * 4);
static const size_t ZERO_BYTES = ZERO_END - OFF_HIST;                  // ~5.25 MB contiguous
static const size_t OFF_PPK  = 10u << 20;      // 16*16384 u64 positive keys
// aopt (16*512 u32 = 32 KB) aliases OFF_PPK: written by k_anchor strictly after
// k_mid consumed ppk (stream-ordered). Verified no live-region overlap.

__device__ __forceinline__ unsigned ordkey(float f) {
  unsigned b = __float_as_uint(f);
  return (b & 0x80000000u) ? ~b : (b | 0x80000000u);   // monotone float->uint
}

__global__ void k_zero(unsigned* __restrict__ p, int n) {
  int stride = gridDim.x * blockDim.x;
  for (int t = blockIdx.x * blockDim.x + threadIdx.x; t < n; t += stride) p[t] = 0u;
}

// ---- fused: transpose + negative bucket histogram (all 1024 blocks, wide)
//      + positive two-level collect (blocks 0-63 extra duty) [R11/R12-validated] ----
__global__ void k_prep2(const float* __restrict__ scores, const int* __restrict__ labels,
                        float* __restrict__ col, unsigned* __restrict__ h1,
                        unsigned* __restrict__ pcnt, unsigned long long* __restrict__ ppk) {
  int t = blockIdx.x * 256 + threadIdx.x;      // 0..262143
  float v = scores[t];
  int i = t >> 4, c = t & 15;
  col[(c << 14) | i] = v;
  if (labels[i] != c)
    atomicAdd(&h1[(c << 16) + (ordkey(v) >> BSH)], 1u);
  if (blockIdx.x < 64) {
    __shared__ unsigned lc[NCLS];
    __shared__ unsigned base[NCLS];
    int tid = threadIdx.x;
    if (tid < NCLS) lc[tid] = 0;
    __syncthreads();
    int ii = blockIdx.x * 256 + tid;   // 0..16383
    int cc = labels[ii] & 15;
    float vv = scores[ii * NCLS + cc];
    unsigned loc = atomicAdd(&lc[cc], 1u);
    __syncthreads();
    if (tid < NCLS) base[tid] = lc[tid] ? atomicAdd(&pcnt[tid], lc[tid]) : 0u;
    __syncthreads();
    ppk[(cc << 14) + base[cc] + loc] = ((unsigned long long)(~ordkey(vv)) << 32) | (unsigned)ii;
  }
}

// ---- merged: blocks 0-15 = per-class 64K-bucket exclusive scan (1024 thr);
//      blocks 16-31 = positive rank (1 block/class, 1024 thr) [R9-validated] ----
#define PCAP 2048
__global__ __launch_bounds__(1024) void k_mid(
    unsigned* __restrict__ h1, const float* __restrict__ col,
    const unsigned* __restrict__ pcnt, const unsigned long long* __restrict__ ppk,
    float* __restrict__ spos) {
  int b = blockIdx.x;
  int tid = threadIdx.x;
  __shared__ unsigned part[1024];
  __shared__ unsigned long long pk[PCAP];
  if (b < NCLS) {
    unsigned* h = h1 + ((size_t)b << 16);
    unsigned base = (unsigned)tid << 6;
    unsigned s = 0;
    for (int q = 0; q < 64; ++q) s += h[base + q];
    part[tid] = s;
    __syncthreads();
    for (int off = 1; off < 1024; off <<= 1) {
      unsigned v = (tid >= off) ? part[tid - off] : 0u;
      __syncthreads();
      part[tid] += v;
      __syncthreads();
    }
    unsigned running = part[tid] - s;   // exclusive prefix of this thread's chunk
    for (int q = 0; q < 64; ++q) {
      unsigned tmp = h[base + q];
      h[base + q] = running;
      running += tmp;
    }
  } else {
    // positive rank: keys unique -> count-smaller is permutation-invariant
    int c = b - NCLS;
    unsigned P = pcnt[c];
    const unsigned long long* src = ppk + ((size_t)c << 14);
    if (P <= PCAP) {
      for (unsigned t = tid; t < P; t += 1024) pk[t] = src[t];
      __syncthreads();
      for (unsigned q = tid; q < P; q += 1024) {
        unsigned long long k64 = pk[q];
        unsigned cq = 0;
        for (unsigned t = 0; t < P; ++t) cq += (pk[t] < k64) ? 1u : 0u;
        unsigned i = (unsigned)(k64 & 0xFFFFFFFFu);
        spos[(c << 14) + cq] = col[(c << 14) + (int)i];
      }
    } else {  // safety fallback (won't trigger for this input)
      for (unsigned q = tid; q < P; q += 1024) {
        unsigned long long k64 = src[q];
        unsigned cq = 0;
        for (unsigned t = 0; t < P; ++t) cq += (src[t] < k64) ? 1u : 0u;
        unsigned i = (unsigned)(k64 & 0xFFFFFFFFu);
        spos[(c << 14) + cq] = col[(c << 14) + (int)i];
      }
    }
  }
}

// ---- scatter negatives (WIDE 1024 blocks; h1[b] becomes bucket END) ----
__global__ void k_scatter(const float* __restrict__ col, const int* __restrict__ labels,
                          unsigned* __restrict__ h1, unsigned* __restrict__ pack) {
  int t = blockIdx.x * 256 + threadIdx.x;
  int c = t >> 14, i = t & 16383;
  if (labels[i] != c) {
    unsigned k = ordkey(col[t]);
    unsigned p = atomicAdd(&h1[(c << 16) + (k >> BSH)], 1u);
    pack[(c << 14) + p] = (k << 16) | (unsigned)i;   // low16 key + idx: unique stable
  }
}

// ---- final rank (WIDE; bucket start + count-smaller in bucket) -> sneg ----
__global__ void k_rankfine(const float* __restrict__ col, const int* __restrict__ labels,
                           const unsigned* __restrict__ h1, const unsigned* __restrict__ pack,
                           float* __restrict__ sneg) {
  int t = blockIdx.x * 256 + threadIdx.x;
  int c = t >> 14, i = t & 16383;
  if (labels[i] != c) {
    float v = col[t];
    unsigned k = ordkey(v);
    unsigned b = k >> BSH;
    const unsigned* hb = h1 + ((size_t)c << 16);
    unsigned start = b ? hb[b - 1] : 0u;   // after scatter: hb[x] = end of bucket x
    unsigned end = hb[b];
    unsigned mine = (k << 16) | (unsigned)i;
    const unsigned* pk = pack + (c << 14);
    unsigned cnt = start;
    for (unsigned q = start; q < end; ++q) cnt += (pk[q] < mine) ? 1u : 0u;
    sneg[(c << 14) + (int)cnt] = v;        // cnt = 0-based ascending rank (unique)
  }
}

// ============================================================================
// opt_j monotone non-increasing in ascending rank j (the property the
// reference's quickselect D&C exploits) => anchors every ASTEP ranks bracket
// every intermediate opt. WIDE anchor kernel (64-lane-packed scans) — R12's
// per-block 5-lane fusion cost +35 us; this form is R9-validated (~10 us).
// ============================================================================
#define SCAP 2048
#define HCAP 2048
#define ASTEP 64
#define ABITS 6

// one thread per anchor, 64-thr blocks, grid (5, NCLS): 320 slots >= T<=257
__global__ void k_anchor(const unsigned* __restrict__ counts, const float* __restrict__ spos,
                         const float* __restrict__ sneg, unsigned* __restrict__ aopt) {
  int c = blockIdx.y;
  int P = (int)counts[c];
  int N = C_ITEMS - P;
  if (P == 0 || N == 0) return;
  int tid = threadIdx.x;
  __shared__ float sp[SCAP];
  int stageN = (P <= SCAP) ? P : 0;
  for (int t = tid; t < stageN; t += 64) sp[t] = spos[(c << 14) + t];
  __syncthreads();
  int ta = blockIdx.x * 64 + tid;
  int T = (N + ASTEP - 1) / ASTEP + 1;      // full anchors + terminal anchor at N-1
  if (ta >= T) return;
  float invP = 1.0f / (float)P;
  float coef = 2.0f / ((float)P * (float)N);
  int j0 = min(ta * ASTEP, N - 1);
  float v = sneg[(c << 14) + j0];
  float a = coef * v;
  float fcnt = (float)(j0 + P + 1);
  float s = 0.0f, best = 0.0f;
  int besti = P;
  if (P <= SCAP) {
    for (int q = P - 1; q >= 0; --q) {
      float spv = sp[q];
      float r = __builtin_amdgcn_rcpf(fcnt);
      float delta = fmaf(invP, r, fmaf(-coef, spv, a));
      s += delta;
      if (s >= best) { best = s; besti = q; }
      fcnt -= 1.0f;
    }
  } else {
    const float* spg = spos + ((size_t)c << 14);
    for (int q = P - 1; q >= 0; --q) {
      float spv = spg[q];
      float r = __builtin_amdgcn_rcpf(fcnt);
      float delta = fmaf(invP, r, fmaf(-coef, spv, a));
      s += delta;
      if (s >= best) { best = s; besti = q; }
      fcnt -= 1.0f;
    }
  }
  aopt[(c << 9) + ta] = (unsigned)(besti + 1);
}

// ---- bracketed per-negative argmax + histogram + minus-side sums [R9-validated] ----
__global__ void k_optB(const unsigned* __restrict__ counts, const float* __restrict__ spos,
                       const float* __restrict__ sneg, const unsigned* __restrict__ aopt,
                       unsigned* __restrict__ hist, double* __restrict__ accS,
                       double* __restrict__ accV) {
  int c = blockIdx.y;
  int P = (int)counts[c];
  int N = C_ITEMS - P;
  if (P == 0 || N == 0) return;
  int tid = threadIdx.x;
  int j0 = blockIdx.x * 256 + tid;
  bool active = (j0 < N);
  __shared__ float sp[SCAP];
  __shared__ unsigned lh[HCAP];
  __shared__ double red[256];
  int stageN = (P <= SCAP) ? P : 0;
  int zn = (P + 2 <= HCAP) ? (P + 2) : 0;
  for (int t = tid; t < stageN; t += 256) sp[t] = spos[(c << 14) + t];
  for (int t = tid; t < zn; t += 256) lh[t] = 0u;
  __syncthreads();
  int opt = P + 1;
  float v = 0.0f;
  if (active) {
    v = sneg[(c << 14) + j0];
    int g = j0 >> ABITS;
    int hiA = (int)aopt[(c << 9) + g];
    if ((j0 & (ASTEP - 1)) == 0) {
      opt = hiA;                      // anchor rank: exact full-scan value
    } else {
      int loA = (int)aopt[(c << 9) + g + 1];
      int hi = min(hiA + 2, P + 1);   // +-2 margin absorbs float near-tie wobble
      int lo = max(loA - 2, 1);
      float invP = 1.0f / (float)P;
      float coef = 2.0f / ((float)P * (float)N);
      float a = coef * v;
      float s = 0.0f, best = 0.0f;
      int bestr = hi;                 // empty suffix (value 0) candidate at r=hi
      float fcnt = (float)(j0 + hi);  // j0+1+k at k=hi-1
      if (P <= SCAP) {
        for (int k = hi - 1; k >= lo; --k) {
          float spv = sp[k - 1];
          float r = __builtin_amdgcn_rcpf(fcnt);
          float delta = fmaf(invP, r, fmaf(-coef, spv, a));
          s += delta;
          if (s >= best) { best = s; bestr = k; }
          fcnt -= 1.0f;
        }
      } else {
        const float* spg = spos + ((size_t)c << 14);
        for (int k = hi - 1; k >= lo; --k) {
          float spv = spg[k - 1];
          float r = __builtin_amdgcn_rcpf(fcnt);
          float delta = fmaf(invP, r, fmaf(-coef, spv, a));
          s += delta;
          if (s >= best) { best = s; bestr = k; }
          fcnt -= 1.0f;
        }
      }
      opt = bestr;
    }
  }
  if (P + 2 <= HCAP) {
    if (active) atomicAdd(&lh[opt], 1u);
    __syncthreads();
    for (int t = tid; t < P + 2; t += 256)
      if (lh[t]) atomicAdd(&hist[c * HSTRIDE + t], lh[t]);
  } else {
    if (active) atomicAdd(&hist[c * HSTRIDE + opt], 1u);
  }
  double cm = active ? (double)(P + 2 - 2 * opt) * (double)v : 0.0;
  double sv = active ? (double)v : 0.0;
  red[tid] = cm; __syncthreads();
  for (int sh = 128; sh > 0; sh >>= 1) { if (tid < sh) red[tid] += red[tid + sh]; __syncthreads(); }
  if (tid == 0) atomicAdd(&accS[c], red[0]);
  __syncthreads();
  red[tid] = sv; __syncthreads();
  for (int sh = 128; sh > 0; sh >>= 1) { if (tid < sh) red[tid] += red[tid + sh]; __syncthreads(); }
  if (tid == 0) atomicAdd(&accV[c], red[0]);
}

// ---- per-class: prefix-sum hist -> r_plus, plus-side sums, loss, final out ----
__global__ void k_fin(const unsigned* __restrict__ counts, const unsigned* __restrict__ hist,
                      const float* __restrict__ spos, const double* __restrict__ accS,
                      const double* __restrict__ accV, double* __restrict__ total,
                      unsigned* __restrict__ done, float* __restrict__ out) {
  int c = blockIdx.x;
  int tid = threadIdx.x;
  int P = (int)counts[c];
  int N = C_ITEMS - P;
  __shared__ unsigned sc[256];
  __shared__ double red[256];
  double lc = 0.0;
  if (P > 0 && N > 0) {
    const unsigned* h = hist + c * HSTRIDE;
    int M = P + 1;
    int L = (M + 255) / 256;
    int o0 = 1 + tid * L;
    int o1 = min(o0 + L, P + 2);
    unsigned part = 0;
    for (int o = o0; o < o1; ++o) part += h[o];
    sc[tid] = part;
    __syncthreads();
    if (tid == 0) {
      unsigned runp = 0;
      for (int t = 0; t < 256; ++t) { unsigned tmp = sc[t]; sc[t] = runp; runp += tmp; }
    }
    __syncthreads();
    unsigned run = sc[tid];
    double a1 = 0.0, a2 = 0.0, a3 = 0.0;
    for (int o = o0; o < o1; ++o) {
      run += h[o];
      if (o <= P) {
        int k0 = o - 1;
        double rp = 1.0 + (double)run;
        double spv = (double)spos[(c << 14) + k0];
        a1 += (double)(k0 + 1) / ((double)k0 + rp);
        a2 += spv * ((double)N + 2.0 - 2.0 * rp);
        a3 += spv;
      }
    }
    red[tid] = a1; __syncthreads();
    for (int s = 128; s > 0; s >>= 1) { if (tid < s) red[tid] += red[tid + s]; __syncthreads(); }
    double r1 = red[0]; __syncthreads();
    red[tid] = a2; __syncthreads();
    for (int s = 128; s > 0; s >>= 1) { if (tid < s) red[tid] += red[tid + s]; __syncthreads(); }
    double r2 = red[0]; __syncthreads();
    red[tid] = a3; __syncthreads();
    for (int s = 128; s > 0; s >>= 1) { if (tid < s) red[tid] += red[tid + s]; __syncthreads(); }
    double r3 = red[0];
    if (tid == 0) {
      double Pd = (double)P, Nd = (double)N;
      double FR  = r2 + accS[c];
      double FRs = Nd * r3 - Pd * accV[c];
      lc = (1.0 - r1 / Pd) + (FR - FRs) / (Pd * Nd);
    }
  }
  if (tid == 0) {
    if (P > 0 && N > 0) atomicAdd(total, lc);
    __threadfence();
    unsigned d = atomicAdd(done, 1u);
    if (d == NCLS - 1) {
      double t = atomicAdd(total, 0.0);  // device-scope RMW: coherent final value
      out[0] = (float)(t / (double)NCLS);
    }
  }
}

extern "C" void kernel_launch(void* const* d_in, const int* in_sizes, int n_in,
                              void* d_out, int out_size, void* d_ws, size_t ws_size,
                              hipStream_t stream) {
  (void)in_sizes; (void)n_in; (void)out_size; (void)ws_size;
  const float* scores = (const float*)d_in[0];
  const int* labels = (const int*)d_in[1];
  float* out = (float*)d_out;
  char* ws = (char*)d_ws;
  float* col      = (float*)(ws + OFF_COL);
  float* spos     = (float*)(ws + OFF_SPOS);
  float* sneg     = (float*)(ws + OFF_SNEG);
  unsigned* pack  = (unsigned*)(ws + OFF_PACK);
  unsigned* hist  = (unsigned*)(ws + OFF_HIST);
  unsigned* done  = (unsigned*)(ws + OFF_CNT);
  double* accS    = (double*)(ws + OFF_ACCS);
  double* accV    = (double*)(ws + OFF_ACCV);
  double* total   = (double*)(ws + OFF_TOT);
  unsigned* pcnt  = (unsigned*)(ws + OFF_PC);   // per-class P counts
  unsigned* h1    = (unsigned*)(ws + OFF_H1);
  unsigned long long* ppk = (unsigned long long*)(ws + OFF_PPK);
  unsigned* aopt  = (unsigned*)(ws + OFF_PPK);  // reused after k_mid consumed ppk

  int zn = (int)(ZERO_BYTES / 4);
  k_zero<<<1024, 256, 0, stream>>>(hist, zn);   // zeroes hist..h1 (contiguous ~5.25 MB)
  k_prep2<<<1024, 256, 0, stream>>>(scores, labels, col, h1, pcnt, ppk);
  k_mid<<<32, 1024, 0, stream>>>(h1, col, pcnt, ppk, spos);
  k_scatter<<<1024, 256, 0, stream>>>(col, labels, h1, pack);
  k_rankfine<<<1024, 256, 0, stream>>>(col, labels, h1, pack, sneg);
  k_anchor<<<dim3(5, NCLS), 64, 0, stream>>>(pcnt, spos, sneg, aopt);
  k_optB<<<dim3(64, NCLS), 256, 0, stream>>>(pcnt, spos, sneg, aopt, hist, accS, accV);
  k_fin<<<NCLS, 256, 0, stream>>>(pcnt, hist, spos, accS, accV, total, done, out);
}